// Round 1
// baseline (39292.120 us; speedup 1.0000x reference)
//
#include <hip/hip_runtime.h>
#include <stdint.h>

#define Bsz 128
#define Lsz 1024
#define Csz 256
#define Hsz 256
#define STRD 264  // padded LDS row stride in bf16 elems: 264*2B = 528B rows, 16B aligned, 2-way-bank only

typedef __attribute__((ext_vector_type(8))) short bf16x8;
typedef __attribute__((ext_vector_type(4))) float f32x4;

__device__ __forceinline__ unsigned short f2bf(float f) {
    union { float f; uint32_t u; } v; v.f = f;
    uint32_t u = v.u;
    return (unsigned short)((u + 0x7FFFu + ((u >> 16) & 1u)) >> 16);  // RNE
}

__device__ __forceinline__ bf16x8 load_wfrag(const float* __restrict__ W, int row, int kb) {
    const float4* p = (const float4*)(W + row * Csz + kb);
    float4 a = p[0];
    float4 b = p[1];
    bf16x8 r;
    r[0] = (short)f2bf(a.x); r[1] = (short)f2bf(a.y);
    r[2] = (short)f2bf(a.z); r[3] = (short)f2bf(a.w);
    r[4] = (short)f2bf(b.x); r[5] = (short)f2bf(b.y);
    r[6] = (short)f2bf(b.z); r[7] = (short)f2bf(b.w);
    return r;
}

__device__ __forceinline__ float sigm(float x) { return 1.0f / (1.0f + __expf(-x)); }
__device__ __forceinline__ float tanhf_(float x) { return 1.0f - 2.0f / (1.0f + __expf(2.0f * x)); }

// 8 WGs x 1024 threads (16 waves). WG g owns batch rows [16g, 16g+16) for the whole
// sequence; no inter-WG communication. Wave w owns gate columns {j, j+256, j+512},
// j in [16w, 16w+16): the r/z/n triple for (row, j) lands in the same lane+reg of the
// three accumulators -> gate math fully in registers. All 4 weight matrices live in
// VGPRs as bf16 MFMA B-fragments (384 VGPRs/lane).
__global__ __launch_bounds__(1024, 4) void gru2_kernel(
    const float* __restrict__ x, const float* __restrict__ h0in,
    const float* __restrict__ wih0, const float* __restrict__ whh0,
    const float* __restrict__ bih0, const float* __restrict__ bhh0,
    const float* __restrict__ wih1, const float* __restrict__ whh1,
    const float* __restrict__ bih1, const float* __restrict__ bhh1,
    float* __restrict__ out)
{
    __shared__ short sx[16 * STRD];   // x_t tile, bf16
    __shared__ short sh0[16 * STRD];  // layer-0 h state, bf16 (fp32 master in regs)
    __shared__ short sh1[16 * STRD];  // layer-1 h state, bf16

    const int tid = threadIdx.x;
    const int wv = tid >> 6;       // wave 0..15
    const int ln = tid & 63;
    const int lrow = ln & 15;      // MFMA m/n lane index
    const int quad = ln >> 4;      // 0..3
    const int b0 = blockIdx.x << 4;
    const int jcol = (wv << 4) | lrow;  // this lane's H-column

    // per-lane biases (fixed j across all steps)
    const float bir0 = bih0[jcol], biz0 = bih0[Hsz + jcol], bin0 = bih0[2 * Hsz + jcol];
    const float bhr0 = bhh0[jcol], bhz0 = bhh0[Hsz + jcol], bhn0 = bhh0[2 * Hsz + jcol];
    const float bir1 = bih1[jcol], biz1 = bih1[Hsz + jcol], bin1 = bih1[2 * Hsz + jcol];
    const float bhr1 = bhh1[jcol], bhz1 = bhh1[Hsz + jcol], bhn1 = bhh1[2 * Hsz + jcol];

    // persistent fp32 h for rows quad*4+q at column jcol (matches MFMA C/D layout:
    // col = lane&15, row = (lane>>4)*4 + reg  [m89-verified])
    float hp0[4], hp1[4];
#pragma unroll
    for (int q = 0; q < 4; ++q) {
        const int r = (quad << 2) + q;
        hp0[q] = h0in[(b0 + r) * Hsz + jcol];
        hp1[q] = h0in[Bsz * Hsz + (b0 + r) * Hsz + jcol];
    }

    // resident weight B-fragments: B[k][n]: lane holds n = lane&15 (abs col g*256+jcol),
    // k = quad*8 + j within a k-tile of 32.
    bf16x8 Wi0[3][8], Wh0[3][8], Wi1[3][8], Wh1[3][8];
#pragma unroll
    for (int g = 0; g < 3; ++g) {
        const int row = g * Hsz + jcol;  // row of W  = gate column
#pragma unroll
        for (int kt = 0; kt < 8; ++kt) {
            const int kb = (kt << 5) + (quad << 3);
            Wi0[g][kt] = load_wfrag(wih0, row, kb);
            Wh0[g][kt] = load_wfrag(whh0, row, kb);
            Wi1[g][kt] = load_wfrag(wih1, row, kb);
            Wh1[g][kt] = load_wfrag(whh1, row, kb);
        }
    }

    // stage initial h into LDS (bf16)
    {
        const int r = tid >> 6;
        const int c4 = (tid & 63) << 2;
        float4 a = *(const float4*)(h0in + (b0 + r) * Hsz + c4);
        float4 b = *(const float4*)(h0in + Bsz * Hsz + (b0 + r) * Hsz + c4);
        ushort4 pa, pb;
        pa.x = f2bf(a.x); pa.y = f2bf(a.y); pa.z = f2bf(a.z); pa.w = f2bf(a.w);
        pb.x = f2bf(b.x); pb.y = f2bf(b.y); pb.z = f2bf(b.z); pb.w = f2bf(b.w);
        *(ushort4*)(&sh0[r * STRD + c4]) = pa;
        *(ushort4*)(&sh1[r * STRD + c4]) = pb;
    }

    const f32x4 zero4 = {0.0f, 0.0f, 0.0f, 0.0f};

#pragma unroll 1
    for (int t = 0; t < Lsz; ++t) {
        // stage x_t (16 rows x 256 cols, coalesced float4 per thread)
        {
            const int r = tid >> 6;
            const int c4 = (tid & 63) << 2;
            float4 a = *(const float4*)(x + ((size_t)(b0 + r) * Lsz + t) * Csz + c4);
            ushort4 p;
            p.x = f2bf(a.x); p.y = f2bf(a.y); p.z = f2bf(a.z); p.w = f2bf(a.w);
            *(ushort4*)(&sx[r * STRD + c4]) = p;
        }
        __syncthreads();  // A: x staged; previous iter's h writes visible

        // ---------------- layer 0 ----------------
        f32x4 ar = zero4, az = zero4, an = zero4;  // gi accumulators (r,z,n)
        f32x4 hr = zero4, hz = zero4, hn = zero4;  // gh accumulators
#pragma unroll
        for (int kt = 0; kt < 8; ++kt) {
            const bf16x8 a = *(const bf16x8*)(&sx[lrow * STRD + (kt << 5) + (quad << 3)]);
            ar = __builtin_amdgcn_mfma_f32_16x16x32_bf16(a, Wi0[0][kt], ar, 0, 0, 0);
            az = __builtin_amdgcn_mfma_f32_16x16x32_bf16(a, Wi0[1][kt], az, 0, 0, 0);
            an = __builtin_amdgcn_mfma_f32_16x16x32_bf16(a, Wi0[2][kt], an, 0, 0, 0);
        }
#pragma unroll
        for (int kt = 0; kt < 8; ++kt) {
            const bf16x8 a = *(const bf16x8*)(&sh0[lrow * STRD + (kt << 5) + (quad << 3)]);
            hr = __builtin_amdgcn_mfma_f32_16x16x32_bf16(a, Wh0[0][kt], hr, 0, 0, 0);
            hz = __builtin_amdgcn_mfma_f32_16x16x32_bf16(a, Wh0[1][kt], hz, 0, 0, 0);
            hn = __builtin_amdgcn_mfma_f32_16x16x32_bf16(a, Wh0[2][kt], hn, 0, 0, 0);
        }
        __syncthreads();  // B: all reads of old sh0 done

#pragma unroll
        for (int q = 0; q < 4; ++q) {
            const float rg = sigm(ar[q] + bir0 + hr[q] + bhr0);
            const float zg = sigm(az[q] + biz0 + hz[q] + bhz0);
            const float ng = tanhf_(an[q] + bin0 + rg * (hn[q] + bhn0));
            const float h = (1.0f - zg) * ng + zg * hp0[q];
            hp0[q] = h;
            sh0[((quad << 2) + q) * STRD + jcol] = (short)f2bf(h);
        }
        __syncthreads();  // C: new h0 visible

        // ---------------- layer 1 (input = new h0) ----------------
        ar = zero4; az = zero4; an = zero4;
        hr = zero4; hz = zero4; hn = zero4;
#pragma unroll
        for (int kt = 0; kt < 8; ++kt) {
            const bf16x8 a = *(const bf16x8*)(&sh0[lrow * STRD + (kt << 5) + (quad << 3)]);
            ar = __builtin_amdgcn_mfma_f32_16x16x32_bf16(a, Wi1[0][kt], ar, 0, 0, 0);
            az = __builtin_amdgcn_mfma_f32_16x16x32_bf16(a, Wi1[1][kt], az, 0, 0, 0);
            an = __builtin_amdgcn_mfma_f32_16x16x32_bf16(a, Wi1[2][kt], an, 0, 0, 0);
        }
#pragma unroll
        for (int kt = 0; kt < 8; ++kt) {
            const bf16x8 a = *(const bf16x8*)(&sh1[lrow * STRD + (kt << 5) + (quad << 3)]);
            hr = __builtin_amdgcn_mfma_f32_16x16x32_bf16(a, Wh1[0][kt], hr, 0, 0, 0);
            hz = __builtin_amdgcn_mfma_f32_16x16x32_bf16(a, Wh1[1][kt], hz, 0, 0, 0);
            hn = __builtin_amdgcn_mfma_f32_16x16x32_bf16(a, Wh1[2][kt], hn, 0, 0, 0);
        }
        __syncthreads();  // D: all reads of old sh1 done

#pragma unroll
        for (int q = 0; q < 4; ++q) {
            const float rg = sigm(ar[q] + bir1 + hr[q] + bhr1);
            const float zg = sigm(az[q] + biz1 + hz[q] + bhz1);
            const float ng = tanhf_(an[q] + bin1 + rg * (hn[q] + bhn1));
            const float h = (1.0f - zg) * ng + zg * hp1[q];
            hp1[q] = h;
            sh1[((quad << 2) + q) * STRD + jcol] = (short)f2bf(h);
            out[((size_t)(b0 + (quad << 2) + q) * Lsz + t) * Hsz + jcol] = h;
        }
        // no sync needed here: next-iter stage touches only sx; barrier A separates
        // these sh1 writes from next iter's layer-1 reads.
    }

    // final hidden states: out tail = hN[2][B][H]
    float* hN = out + (size_t)Bsz * Lsz * Hsz;
#pragma unroll
    for (int q = 0; q < 4; ++q) {
        const int r = (quad << 2) + q;
        hN[(b0 + r) * Hsz + jcol] = hp0[q];
        hN[Bsz * Hsz + (b0 + r) * Hsz + jcol] = hp1[q];
    }
}

extern "C" void kernel_launch(void* const* d_in, const int* in_sizes, int n_in,
                              void* d_out, int out_size, void* d_ws, size_t ws_size,
                              hipStream_t stream) {
    const float* xx   = (const float*)d_in[0];
    const float* h0   = (const float*)d_in[1];
    const float* wih0 = (const float*)d_in[2];
    const float* whh0 = (const float*)d_in[3];
    const float* bih0 = (const float*)d_in[4];
    const float* bhh0 = (const float*)d_in[5];
    const float* wih1 = (const float*)d_in[6];
    const float* whh1 = (const float*)d_in[7];
    const float* bih1 = (const float*)d_in[8];
    const float* bhh1 = (const float*)d_in[9];
    float* out = (float*)d_out;
    gru2_kernel<<<dim3(8), dim3(1024), 0, stream>>>(xx, h0, wih0, whh0, bih0, bhh0,
                                                    wih1, whh1, bih1, bhh1, out);
}

// Round 2
// 12974.825 us; speedup vs baseline: 3.0283x; 3.0283x over previous
//
#include <hip/hip_runtime.h>
#include <stdint.h>

#define Bsz 128
#define Lsz 1024
#define Hsz 256
#define HB  (Bsz * Hsz)   // 32768 elems = one parity buffer

typedef __attribute__((ext_vector_type(8))) short bf16x8;
typedef __attribute__((ext_vector_type(4))) float f32x4;

__device__ __forceinline__ unsigned short f2bf(float f) {
    union { float f; uint32_t u; } v; v.f = f;
    uint32_t u = v.u;
    return (unsigned short)((u + 0x7FFFu + ((u >> 16) & 1u)) >> 16);  // RNE
}

__device__ __forceinline__ bf16x8 load_wfrag(const float* __restrict__ W, int row, int kb) {
    const float4* p = (const float4*)(W + row * Hsz + kb);
    float4 a = p[0], b = p[1];
    bf16x8 r;
    r[0] = (short)f2bf(a.x); r[1] = (short)f2bf(a.y);
    r[2] = (short)f2bf(a.z); r[3] = (short)f2bf(a.w);
    r[4] = (short)f2bf(b.x); r[5] = (short)f2bf(b.y);
    r[6] = (short)f2bf(b.z); r[7] = (short)f2bf(b.w);
    return r;
}

__device__ __forceinline__ float sigm(float x) { return 1.0f / (1.0f + __expf(-x)); }
__device__ __forceinline__ float tanhf_(float x) { return 1.0f - 2.0f / (1.0f + __expf(2.0f * x)); }

__device__ __forceinline__ void mm_step(bf16x8 a, const bf16x8 (&W)[3][8], int kt,
                                        f32x4& r, f32x4& z, f32x4& n) {
    r = __builtin_amdgcn_mfma_f32_16x16x32_bf16(a, W[0][kt], r, 0, 0, 0);
    z = __builtin_amdgcn_mfma_f32_16x16x32_bf16(a, W[1][kt], z, 0, 0, 0);
    n = __builtin_amdgcn_mfma_f32_16x16x32_bf16(a, W[2][kt], n, 0, 0, 0);
}

// all 64 lanes poll flag[ln&15]; relaxed spin then one acquire (buffer_inv) to
// make the producers' h-buf stores visible through this CU's L1.
__device__ __forceinline__ void waitflags16(int* f, int target, int ln) {
    const int idx = ln & 15;
    while (__hip_atomic_load(f + idx, __ATOMIC_RELAXED, __HIP_MEMORY_SCOPE_AGENT) < target) { }
    (void)__hip_atomic_load(f + idx, __ATOMIC_ACQUIRE, __HIP_MEMORY_SCOPE_AGENT);
}

__global__ void init_ws(const float* __restrict__ h0in, int* flags,
                        unsigned short* h0buf, unsigned short* h1buf) {
    int i = blockIdx.x * blockDim.x + threadIdx.x;  // 0..32767
    if (i < 256) flags[i] = 0;                      // flags0[128] + flags1[128]
    h0buf[HB + i] = f2bf(h0in[i]);                  // parity-1 buffers hold h(-1)
    h1buf[HB + i] = f2bf(h0in[HB + i]);
}

// Persistent 2-layer GRU. Grid 64 = 8 batch-groups x 8 column-parts; part p of
// group g has blockIdx = p*8+g so all parts of a group land on XCD g (L2-local
// h exchange). 512 threads = 8 waves: wave = (mat = wv&3, jt = wv>>2).
// mat: 0=W_ih0 (gi0), 1=W_hh0 (gh0 + layer-0 gate owner), 2=W_ih1 (gi1),
//      3=W_hh1 (gh1 + layer-1 gate owner). Each wave's weight slice: 3 gates x
// 16 cols x 256 K bf16 = 24 frags = 96 VGPRs, register-resident (no spill: cap
// 256 at 2 waves/SIMD).
__global__ __launch_bounds__(512, 2) void gru2_persist(
    const float* __restrict__ x, const float* __restrict__ h0in,
    const float* __restrict__ wih0, const float* __restrict__ whh0,
    const float* __restrict__ bih0, const float* __restrict__ bhh0,
    const float* __restrict__ wih1, const float* __restrict__ whh1,
    const float* __restrict__ bih1, const float* __restrict__ bhh1,
    float* __restrict__ out,
    int* flags0, unsigned short* h0buf, unsigned short* h1buf)
{
    __shared__ float lds0[3][2][16][16];  // gi0 accums: [gate][jt][row][col]
    __shared__ float lds1[3][2][16][16];  // gi1 accums

    const int tid = threadIdx.x;
    const int wv = tid >> 6, ln = tid & 63;
    const int lr = ln & 15, quad = ln >> 4;
    const int g = blockIdx.x & 7, p = blockIdx.x >> 3;
    const int mat = wv & 3, jt = wv >> 2;
    const int b0 = g << 4;                         // batch rows [b0, b0+16)
    const int jabs = (p << 5) + (jt << 4) + lr;    // this lane's H column
    int* flags1 = flags0 + 128;
    int* f0g = flags0 + (g << 4);
    int* f1g = flags1 + (g << 4);

    // resident weight slice for this wave's matrix
    const float* Wm = (mat == 0) ? wih0 : (mat == 1) ? whh0 : (mat == 2) ? wih1 : whh1;
    bf16x8 Wf[3][8];
#pragma unroll
    for (int gg = 0; gg < 3; ++gg)
#pragma unroll
        for (int kt = 0; kt < 8; ++kt)
            Wf[gg][kt] = load_wfrag(Wm, gg * Hsz + jabs, (kt << 5) + (quad << 3));

    // gate-owner waves: fp32 h master (C/D layout: col=lane&15, row=quad*4+q) + biases
    float hp[4] = {0.f, 0.f, 0.f, 0.f};
    float bsr = 0.f, bsz_ = 0.f, bin_ = 0.f, bhn_ = 0.f;
    if (mat == 1) {
#pragma unroll
        for (int q = 0; q < 4; ++q) hp[q] = h0in[(b0 + (quad << 2) + q) * Hsz + jabs];
        bsr = bih0[jabs] + bhh0[jabs];
        bsz_ = bih0[Hsz + jabs] + bhh0[Hsz + jabs];
        bin_ = bih0[2 * Hsz + jabs];
        bhn_ = bhh0[2 * Hsz + jabs];
    } else if (mat == 3) {
#pragma unroll
        for (int q = 0; q < 4; ++q) hp[q] = h0in[HB + (b0 + (quad << 2) + q) * Hsz + jabs];
        bsr = bih1[jabs] + bhh1[jabs];
        bsz_ = bih1[Hsz + jabs] + bhh1[Hsz + jabs];
        bin_ = bih1[2 * Hsz + jabs];
        bhn_ = bhh1[2 * Hsz + jabs];
    }

    // x prefetch (mat==0 only): one step ahead, raw fp32 in regs (64 VGPRs)
    const float* xrow = x + (size_t)(b0 + lr) * Lsz * Hsz;  // + t*256 + k
    float4 xpre[16];
    if (mat == 0) {
#pragma unroll
        for (int kt = 0; kt < 8; ++kt) {
            const float* s = xrow + (kt << 5) + (quad << 3);
            xpre[2 * kt] = *(const float4*)(s);
            xpre[2 * kt + 1] = *(const float4*)(s + 4);
        }
    }

#pragma unroll 1
    for (int t = 0; t < Lsz; ++t) {
        const int par_w = t & 1;
        const unsigned short* h0r = h0buf + (par_w ^ 1) * HB;
        unsigned short* h0w = h0buf + par_w * HB;
        const unsigned short* h1r = h1buf + (par_w ^ 1) * HB;
        unsigned short* h1w = h1buf + par_w * HB;

        f32x4 ar = {0.f, 0.f, 0.f, 0.f}, az = {0.f, 0.f, 0.f, 0.f}, an = {0.f, 0.f, 0.f, 0.f};

        // ---- stage 1 ----
        if (mat == 0) {                       // gi0 = x_t @ Wih0^T (prefetched x)
#pragma unroll
            for (int kt = 0; kt < 8; ++kt) {
                float4 u = xpre[2 * kt], v = xpre[2 * kt + 1];
                bf16x8 a;
                a[0] = (short)f2bf(u.x); a[1] = (short)f2bf(u.y);
                a[2] = (short)f2bf(u.z); a[3] = (short)f2bf(u.w);
                a[4] = (short)f2bf(v.x); a[5] = (short)f2bf(v.y);
                a[6] = (short)f2bf(v.z); a[7] = (short)f2bf(v.w);
                mm_step(a, Wf, kt, ar, az, an);
            }
#pragma unroll
            for (int q = 0; q < 4; ++q) {
                lds0[0][jt][(quad << 2) + q][lr] = ar[q];
                lds0[1][jt][(quad << 2) + q][lr] = az[q];
                lds0[2][jt][(quad << 2) + q][lr] = an[q];
            }
        } else if (mat == 1) {                // gh0 = h0(t-1) @ Whh0^T
            waitflags16(f0g, t, ln);
#pragma unroll
            for (int kt = 0; kt < 8; ++kt) {
                bf16x8 a = *(const bf16x8*)(h0r + (b0 + lr) * Hsz + (kt << 5) + (quad << 3));
                mm_step(a, Wf, kt, ar, az, an);
            }
        } else if (mat == 3) {                // gh1 = h1(t-1) @ Whh1^T (overlaps layer 0)
            waitflags16(f1g, t, ln);
#pragma unroll
            for (int kt = 0; kt < 8; ++kt) {
                bf16x8 a = *(const bf16x8*)(h1r + (b0 + lr) * Hsz + (kt << 5) + (quad << 3));
                mm_step(a, Wf, kt, ar, az, an);
            }
        }
        __syncthreads();  // barrier 1: lds0 ready; lds1 free for reuse

        // ---- stage 2 ----
        if (mat == 1) {                       // layer-0 gates -> h0(t), broadcast
#pragma unroll
            for (int q = 0; q < 4; ++q) {
                float gir = lds0[0][jt][(quad << 2) + q][lr];
                float giz = lds0[1][jt][(quad << 2) + q][lr];
                float gin = lds0[2][jt][(quad << 2) + q][lr];
                float r = sigm(gir + ar[q] + bsr);
                float z = sigm(giz + az[q] + bsz_);
                float n = tanhf_(gin + bin_ + r * (an[q] + bhn_));
                float h = (1.0f - z) * n + z * hp[q];
                hp[q] = h;
                h0w[(b0 + (quad << 2) + q) * Hsz + jabs] = f2bf(h);
            }
            if (ln == 0)
                __hip_atomic_store(f0g + (p << 1) + jt, t + 1,
                                   __ATOMIC_RELEASE, __HIP_MEMORY_SCOPE_AGENT);
        } else if (mat == 2) {                // gi1 = h0(t) @ Wih1^T
            waitflags16(f0g, t + 1, ln);
#pragma unroll
            for (int kt = 0; kt < 8; ++kt) {
                bf16x8 a = *(const bf16x8*)(h0w + (b0 + lr) * Hsz + (kt << 5) + (quad << 3));
                mm_step(a, Wf, kt, ar, az, an);
            }
#pragma unroll
            for (int q = 0; q < 4; ++q) {
                lds1[0][jt][(quad << 2) + q][lr] = ar[q];
                lds1[1][jt][(quad << 2) + q][lr] = az[q];
                lds1[2][jt][(quad << 2) + q][lr] = an[q];
            }
        } else if (mat == 0) {                // prefetch x(t+1)
            const int tp = (t + 1 < Lsz) ? (t + 1) : t;
            const float* xb = xrow + (size_t)tp * Hsz;
#pragma unroll
            for (int kt = 0; kt < 8; ++kt) {
                const float* s = xb + (kt << 5) + (quad << 3);
                xpre[2 * kt] = *(const float4*)(s);
                xpre[2 * kt + 1] = *(const float4*)(s + 4);
            }
        }
        __syncthreads();  // barrier 2: lds1 ready

        // ---- stage 3 ----
        if (mat == 3) {                       // layer-1 gates -> h1(t), broadcast + output
            float hv[4];
#pragma unroll
            for (int q = 0; q < 4; ++q) {
                float gir = lds1[0][jt][(quad << 2) + q][lr];
                float giz = lds1[1][jt][(quad << 2) + q][lr];
                float gin = lds1[2][jt][(quad << 2) + q][lr];
                float r = sigm(gir + ar[q] + bsr);
                float z = sigm(giz + az[q] + bsz_);
                float n = tanhf_(gin + bin_ + r * (an[q] + bhn_));
                float h = (1.0f - z) * n + z * hp[q];
                hp[q] = h;
                hv[q] = h;
                h1w[(b0 + (quad << 2) + q) * Hsz + jabs] = f2bf(h);
            }
            if (ln == 0)                       // release BEFORE output stores (flag guards h1buf only)
                __hip_atomic_store(f1g + (p << 1) + jt, t + 1,
                                   __ATOMIC_RELEASE, __HIP_MEMORY_SCOPE_AGENT);
#pragma unroll
            for (int q = 0; q < 4; ++q)
                out[((size_t)(b0 + (quad << 2) + q) * Lsz + t) * Hsz + jabs] = hv[q];
        }
    }

    // final hidden states: out tail = hN[2][B][H]
    float* hN = out + (size_t)Bsz * Lsz * Hsz;
    if (mat == 1) {
#pragma unroll
        for (int q = 0; q < 4; ++q)
            hN[(b0 + (quad << 2) + q) * Hsz + jabs] = hp[q];
    } else if (mat == 3) {
#pragma unroll
        for (int q = 0; q < 4; ++q)
            hN[HB + (b0 + (quad << 2) + q) * Hsz + jabs] = hp[q];
    }
}

extern "C" void kernel_launch(void* const* d_in, const int* in_sizes, int n_in,
                              void* d_out, int out_size, void* d_ws, size_t ws_size,
                              hipStream_t stream) {
    const float* xx   = (const float*)d_in[0];
    const float* h0   = (const float*)d_in[1];
    const float* wih0 = (const float*)d_in[2];
    const float* whh0 = (const float*)d_in[3];
    const float* bih0 = (const float*)d_in[4];
    const float* bhh0 = (const float*)d_in[5];
    const float* wih1 = (const float*)d_in[6];
    const float* whh1 = (const float*)d_in[7];
    const float* bih1 = (const float*)d_in[8];
    const float* bhh1 = (const float*)d_in[9];
    float* out = (float*)d_out;

    int* flags = (int*)d_ws;                                    // 256 ints
    unsigned short* h0buf = (unsigned short*)((char*)d_ws + 4096);   // [2][128][256] bf16
    unsigned short* h1buf = h0buf + 2 * HB;                          // [2][128][256] bf16

    init_ws<<<dim3(128), dim3(256), 0, stream>>>(h0, flags, h0buf, h1buf);
    gru2_persist<<<dim3(64), dim3(512), 0, stream>>>(xx, h0, wih0, whh0, bih0, bhh0,
                                                     wih1, whh1, bih1, bhh1, out,
                                                     flags, h0buf, h1buf);
}